// Round 5
// baseline (283.017 us; speedup 1.0000x reference)
//
#include <hip/hip_runtime.h>
#include <hip/hip_bf16.h>
#include <stdint.h>
#include <stddef.h>

#define S_LEN 2048
#define HIDDEN 2048
#define NHEAD 32
#define NKVH 8
#define DHEAD 64
#define BATCH 2
#define HALFW 512
// 0.125 (1/sqrt(64)) * log2(e) folded into Q at RoPE time
#define QSCALE 0.18033688011112042f

typedef __attribute__((ext_vector_type(4))) float f32x4;
typedef __attribute__((ext_vector_type(8))) short short8;
typedef __attribute__((ext_vector_type(4))) short short4v;
typedef __attribute__((ext_vector_type(2))) unsigned int u32x2;

__device__ __forceinline__ unsigned short f2bf(float f) {
  unsigned u = __builtin_bit_cast(unsigned, f);
  u += 0x7fffu + ((u >> 16) & 1u);
  return (unsigned short)(u >> 16);
}
__device__ __forceinline__ float bf2f(unsigned short h) {
  unsigned u = ((unsigned)h) << 16;
  return __builtin_bit_cast(float, u);
}
__device__ __forceinline__ unsigned cvt_pk_bf16(float lo, float hi) {
  unsigned r;
  asm("v_cvt_pk_bf16_f32 %0, %1, %2" : "=v"(r) : "v"(lo), "v"(hi));
  return r;
}

// ---------------- merged f32 -> bf16 convert for all 5 tensors ----------------
// segments (in float4 units): hs 2097152 | Wq 1048576 | Wk 262144 | Wv 262144 | Wo 1048576
// total 4718592 units = 2048 blocks * 256 threads * 9 iters exactly.
__global__ void k_cvt5(const float* __restrict__ s0, const float* __restrict__ s1,
                       const float* __restrict__ s2, const float* __restrict__ s3,
                       const float* __restrict__ s4,
                       unsigned short* __restrict__ d0, unsigned short* __restrict__ d1,
                       unsigned short* __restrict__ d2, unsigned short* __restrict__ d3,
                       unsigned short* __restrict__ d4) {
  int i = blockIdx.x * blockDim.x + threadIdx.x;
#pragma unroll 1
  for (int it = 0; it < 9; ++it, i += 524288) {
    const float* src;
    unsigned short* dst;
    int base;
    if (i < 2097152)      { src = s0; dst = d0; base = 0; }
    else if (i < 3145728) { src = s1; dst = d1; base = 2097152; }
    else if (i < 3407872) { src = s2; dst = d2; base = 3145728; }
    else if (i < 3670016) { src = s3; dst = d3; base = 3407872; }
    else                  { src = s4; dst = d4; base = 3670016; }
    int j = i - base;
    float4 v = reinterpret_cast<const float4*>(src)[j];
    short4v o;
    o[0] = (short)f2bf(v.x);
    o[1] = (short)f2bf(v.y);
    o[2] = (short)f2bf(v.z);
    o[3] = (short)f2bf(v.w);
    reinterpret_cast<short4v*>(dst)[j] = o;
  }
}

// ---------------- bf16 GEMM: C[M,N] = A[M,K] * W[N,K]^T ----------------
// 256x256 tile, 8 waves (2M x 4N, each 128x64 of C), K pipelined in 32-wide
// halves across 4 LDS slots (3 stages in flight, counted vmcnt(12) -- never
// drained to 0 in the main loop). LDS unit mapping makes ds_read_b128
// bank-conflict-free; global source is permuted instead of the LDS dest
// (global_load_lds writes linearly). 2 raw s_barriers per phase.
template <int CSTORE_F32>
__global__ __launch_bounds__(512, 2) void k_gemm8(const unsigned short* __restrict__ A,
                                                  const unsigned short* __restrict__ Bw,
                                                  void* __restrict__ Cout,
                                                  int M, int N, int K, int ntx) {
  __shared__ unsigned short As[4][8192];   // 4 slots x 16KB (256 rows x 32 k)
  __shared__ unsigned short Bs[4][8192];
  const int tid = threadIdx.x;
  const int w = tid >> 6, lane = tid & 63;
  const int l15 = lane & 15, lhi = lane >> 4;
  const int wm = w >> 2, wn = w & 3;

  // XCD-chunked swizzle (grid divisible by 8)
  const int cpx = (int)gridDim.x >> 3;
  const int bid = blockIdx.x;
  const int swz = (bid & 7) * cpx + (bid >> 3);
  const int ty = swz / ntx, tx = swz - ty * ntx;
  const int bm = ty * 256, bn = tx * 256;

  const int NH = K >> 5;   // number of 32-wide K halves

  // unit u = (row&7) | (c16<<3) | ((row>>3)<<5); read byte addr:
  const int abase = (l15 & 7) * 16 + lhi * 128 + (l15 >> 3) * 512 + wm * 8192;
  const int bbase = (l15 & 7) * 16 + lhi * 128 + (l15 >> 3) * 512 + wn * 4096;

  f32x4 acc[8][4] = {};

  auto stage = [&](int hs) {
    const int kb = hs << 5;
    const int sl = hs & 3;
#pragma unroll
    for (int i = 0; i < 2; ++i) {
      int u = i * 512 + tid;
      int row = (u & 7) | ((u >> 5) << 3);
      int c16 = (u >> 3) & 3;
      __builtin_amdgcn_global_load_lds(
          (const __attribute__((address_space(1))) unsigned int*)(const void*)
              (A + (size_t)(bm + row) * K + kb + c16 * 8),
          (__attribute__((address_space(3))) unsigned int*)(void*)
              ((char*)&As[sl][0] + u * 16),
          16, 0, 0);
      __builtin_amdgcn_global_load_lds(
          (const __attribute__((address_space(1))) unsigned int*)(const void*)
              (Bw + (size_t)(bn + row) * K + kb + c16 * 8),
          (__attribute__((address_space(3))) unsigned int*)(void*)
              ((char*)&Bs[sl][0] + u * 16),
          16, 0, 0);
    }
  };

  auto compute = [&](int hh) {
    const int sl = hh & 3;
    const char* ap = (const char*)&As[sl][0] + abase;
    const char* bp = (const char*)&Bs[sl][0] + bbase;
    short8 av[8], bv[4];
#pragma unroll
    for (int mf = 0; mf < 8; ++mf) av[mf] = *(const short8*)(ap + mf * 1024);
#pragma unroll
    for (int nf = 0; nf < 4; ++nf) bv[nf] = *(const short8*)(bp + nf * 1024);
    __builtin_amdgcn_s_setprio(1);
#pragma unroll
    for (int mf = 0; mf < 8; ++mf)
#pragma unroll
      for (int nf = 0; nf < 4; ++nf)
        acc[mf][nf] = __builtin_amdgcn_mfma_f32_16x16x32_bf16(av[mf], bv[nf], acc[mf][nf], 0, 0, 0);
    __builtin_amdgcn_s_setprio(0);
    __builtin_amdgcn_sched_barrier(0);
    __builtin_amdgcn_s_barrier();        // reads of slot hh done before it is restaged
    __builtin_amdgcn_sched_barrier(0);
  };

  // prologue: 3 halves in flight
  stage(0); stage(1); stage(2);

  for (int h = 0; h < NH - 3; ++h) {
    stage(h + 3);
    asm volatile("s_waitcnt vmcnt(12)" ::: "memory");  // retire half h (in-order), keep 3 staged
    __builtin_amdgcn_s_barrier();                      // all waves confirmed half h in LDS
    __builtin_amdgcn_sched_barrier(0);
    compute(h);
  }
  asm volatile("s_waitcnt vmcnt(8)" ::: "memory");
  __builtin_amdgcn_s_barrier();
  __builtin_amdgcn_sched_barrier(0);
  compute(NH - 3);
  asm volatile("s_waitcnt vmcnt(4)" ::: "memory");
  __builtin_amdgcn_s_barrier();
  __builtin_amdgcn_sched_barrier(0);
  compute(NH - 2);
  asm volatile("s_waitcnt vmcnt(0)" ::: "memory");
  __builtin_amdgcn_s_barrier();
  __builtin_amdgcn_sched_barrier(0);
  compute(NH - 1);

#pragma unroll
  for (int mf = 0; mf < 8; ++mf) {
#pragma unroll
    for (int r = 0; r < 4; ++r) {
      int row = bm + wm * 128 + mf * 16 + lhi * 4 + r;
#pragma unroll
      for (int nf = 0; nf < 4; ++nf) {
        int col = bn + wn * 64 + nf * 16 + l15;
        float v = acc[mf][nf][r];
        if (CSTORE_F32)
          ((float*)Cout)[(size_t)row * N + col] = v;
        else
          ((unsigned short*)Cout)[(size_t)row * N + col] = f2bf(v);
      }
    }
  }
}

// ---------------- RoPE + transpose to (b,h,s,d) for Q and K ----------------
// thread per (b,s,hh,d) with d in [0,32); hh in [0,40): 0..31 = Q heads, 32..39 = K heads
// Q additionally scaled by QSCALE (attention scale * log2e folded in).
__global__ void k_rope(const unsigned short* __restrict__ qkv,
                       const float* __restrict__ cosb, const float* __restrict__ sinb,
                       unsigned short* __restrict__ Qr, unsigned short* __restrict__ Kr) {
  int idx = blockIdx.x * blockDim.x + threadIdx.x;
  if (idx >= BATCH * S_LEN * 40 * 32) return;
  int d = idx & 31;
  int hh = (idx >> 5) % 40;
  int bs = idx / (40 * 32);
  int s = bs % S_LEN, b = bs / S_LEN;
  int row = b * S_LEN + s;
  float c = cosb[row * DHEAD + d];
  float sn = sinb[row * DHEAD + d];
  int col = (hh < 32) ? (hh * DHEAD + d) : (2048 + (hh - 32) * DHEAD + d);
  const unsigned short* p = qkv + (size_t)row * 3072;
  float x1 = bf2f(p[col]);
  float x2 = bf2f(p[col + 32]);
  float o1 = x1 * c - x2 * sn;
  float o2 = x2 * c + x1 * sn;
  if (hh < 32) {
    size_t o = ((size_t)(b * NHEAD + hh) * S_LEN + s) * DHEAD + d;
    Qr[o] = f2bf(o1 * QSCALE);
    Qr[o + 32] = f2bf(o2 * QSCALE);
  } else {
    size_t o = ((size_t)(b * NKVH + (hh - 32)) * S_LEN + s) * DHEAD + d;
    Kr[o] = f2bf(o1);
    Kr[o + 32] = f2bf(o2);
  }
}

// ---------------- V transpose: (b,s,hk,d) slice of QKV -> Vt (b,hk,d,s) ----------------
__global__ void k_vt(const unsigned short* __restrict__ qkv, unsigned short* __restrict__ Vt) {
  __shared__ unsigned short t[64][68];   // 64 s-rows x 64 d-cols, padded
  int s0 = blockIdx.x * 64;
  int b = blockIdx.y >> 3, hk = blockIdx.y & 7;
  int tid = threadIdx.x;
#pragma unroll
  for (int it = 0; it < 4; ++it) {
    int u = it * 256 + tid;
    int srow = u >> 4, c4 = u & 15;
    short4v v = *reinterpret_cast<const short4v*>(
        &qkv[(size_t)(b * S_LEN + s0 + srow) * 3072 + 2560 + hk * 64 + c4 * 4]);
    *reinterpret_cast<short4v*>(&t[srow][c4 * 4]) = v;
  }
  __syncthreads();
#pragma unroll
  for (int it = 0; it < 4; ++it) {
    int u = it * 256 + tid;
    int d = u >> 4, s4 = u & 15;
    short4v v;
#pragma unroll
    for (int j = 0; j < 4; ++j) v[j] = t[s4 * 4 + j][d];
    *reinterpret_cast<short4v*>(
        &Vt[((size_t)(b * NKVH + hk) * DHEAD + d) * S_LEN + s0 + s4 * 4]) = v;
  }
}

// ---------------- sliding-window attention (swapped-QK, packed P) ----------------
__global__ __launch_bounds__(256, 4) void k_attn(const unsigned short* __restrict__ Qr,
                                                 const unsigned short* __restrict__ Kr,
                                                 const unsigned short* __restrict__ Vt,
                                                 unsigned short* __restrict__ AO) {
  __shared__ unsigned short Ks[2][64][64];  // [buf][key][dh]   8KB each
  __shared__ unsigned short Vs[2][64][64];  // [buf][d][key]    8KB each
  __shared__ unsigned short Pl[4][16][64];  // per-wave P, XOR-swizzled, no pad

  const int tid = threadIdx.x, w = tid >> 6, lane = tid & 63;
  const int l15 = lane & 15, lhi = lane >> 4;

  // XCD-chunked bijective swizzle: 2048 blocks, 256 consecutive logical ids
  // per XCD => each XCD's L2 sees only 2 (b,hk) K/V working sets.
  int p = blockIdx.x;
  int L = (p & 7) * 256 + (p >> 3);
  int g = L >> 7;                 // 16 groups of 128 blocks: (b, hk)
  int b = g >> 3, hk = g & 7;
  int r_ = L & 127;
  int h = hk * 4 + (r_ >> 5);
  int q0b = (r_ & 31) * 64;       // block q base (64 rows)
  const int qw = q0b + w * 16;    // wave q base (16 rows)

  const unsigned short* Qh = Qr + (size_t)(b * NHEAD + h) * S_LEN * DHEAD;
  const unsigned short* Kh = Kr + (size_t)(b * NKVH + hk) * S_LEN * DHEAD;
  const unsigned short* Vh = Vt + (size_t)(b * NKVH + hk) * DHEAD * S_LEN;

  short8 qf[2];
#pragma unroll
  for (int c = 0; c < 2; ++c)
    qf[c] = *reinterpret_cast<const short8*>(&Qh[(size_t)(qw + l15) * DHEAD + c * 32 + lhi * 8]);

  f32x4 o[4] = {};
  float den = 0.f;
  const int q = qw + l15;          // this lane's q-row (swapped layout)
  const int kvisLo = q - HALFW, kvisHi = q + HALFW;

  char* plbase = (char*)&Pl[w][0][0];
  const int swzp = (l15 & 7) << 4;

  // block-uniform window (union over 64 q-rows); tiles 64-aligned, never cross S
  int klo = q0b - HALFW; if (klo < 0) klo = 0;
  klo &= ~63;
  int khi = q0b + 63 + HALFW; if (khi > S_LEN - 1) khi = S_LEN - 1;
  const int nt = ((khi + 1 - klo) + 63) >> 6;

  // stage one 64-key tile: K (rows=key) and V (rows=d), source chunk
  // pre-swizzled by (row&7) so LDS dest stays linear (global_load_lds req).
  auto stage = [&](int bufidx, int kbb) {
#pragma unroll
    for (int i = 0; i < 2; ++i) {
      int u = i * 256 + tid;           // 512 16B units
      int row = u >> 3, c16 = u & 7;
      int sc = c16 ^ (row & 7);
      __builtin_amdgcn_global_load_lds(
          (const __attribute__((address_space(1))) unsigned int*)(const void*)
              (Kh + (size_t)(kbb + row) * DHEAD + sc * 8),
          (__attribute__((address_space(3))) unsigned int*)(void*)
              ((char*)&Ks[bufidx][0][0] + u * 16),
          16, 0, 0);
      __builtin_amdgcn_global_load_lds(
          (const __attribute__((address_space(1))) unsigned int*)(const void*)
              (Vh + (size_t)row * S_LEN + kbb + sc * 8),
          (__attribute__((address_space(3))) unsigned int*)(void*)
              ((char*)&Vs[bufidx][0][0] + u * 16),
          16, 0, 0);
    }
  };

  int cur = 0;
  stage(0, klo);
  __syncthreads();

  for (int t = 0; t < nt; ++t) {
    const int kb = klo + t * 64;
    if (t + 1 < nt) stage(cur ^ 1, kb + 64);   // prefetch next tile (in flight across compute)

    // ---- QK^T (swapped): C[key][q], lane holds q=l15, keys 16hh+4lhi+r ----
    f32x4 sacc[4] = {};
    __builtin_amdgcn_s_setprio(1);
#pragma unroll
    for (int hh = 0; hh < 4; ++hh) {
      int kr = hh * 16 + l15;
      const char* kbase = (const char*)&Ks[cur][0][0] + kr * 128;
      short8 kf0 = *reinterpret_cast<const short8*>(kbase + ((lhi ^ (kr & 7)) * 16));
      short8 kf1 = *reinterpret_cast<const short8*>(kbase + (((4 + lhi) ^ (kr & 7)) * 16));
      sacc[hh] = __builtin_amdgcn_mfma_f32_16x16x32_bf16(kf0, qf[0], sacc[hh], 0, 0, 0);
      sacc[hh] = __builtin_amdgcn_mfma_f32_16x16x32_bf16(kf1, qf[1], sacc[hh], 0, 0, 0);
    }
    __builtin_amdgcn_s_setprio(0);

    // ---- softmax numerator: exp2 (Q pre-scaled), pack pairs, ds_write_b64 ----
    const bool inter = (kb >= qw + 15 - HALFW) && (kb + 63 <= qw + HALFW);
    if (inter) {
#pragma unroll
      for (int hh = 0; hh < 4; ++hh) {
        float p0 = __builtin_amdgcn_exp2f(sacc[hh][0]);
        float p1 = __builtin_amdgcn_exp2f(sacc[hh][1]);
        float p2 = __builtin_amdgcn_exp2f(sacc[hh][2]);
        float p3 = __builtin_amdgcn_exp2f(sacc[hh][3]);
        den += (p0 + p1) + (p2 + p3);
        u32x2 pw;
        pw[0] = cvt_pk_bf16(p0, p1);
        pw[1] = cvt_pk_bf16(p2, p3);
        *(u32x2*)(plbase + ((l15 * 128 + hh * 32 + lhi * 8) ^ swzp)) = pw;
      }
    } else {
#pragma unroll
      for (int hh = 0; hh < 4; ++hh) {
        float pp[4];
#pragma unroll
        for (int r = 0; r < 4; ++r) {
          int key = kb + hh * 16 + lhi * 4 + r;
          bool vis = (key >= kvisLo) && (key <= kvisHi);
          pp[r] = vis ? __builtin_amdgcn_exp2f(sacc[hh][r]) : 0.0f;
        }
        den += (pp[0] + pp[1]) + (pp[2] + pp[3]);
        u32x2 pw;
        pw[0] = cvt_pk_bf16(pp[0], pp[1]);
        pw[1] = cvt_pk_bf16(pp[2], pp[3]);
        *(u32x2*)(plbase + ((l15 * 128 + hh * 32 + lhi * 8) ^ swzp)) = pw;
      }
    }
    asm volatile("s_waitcnt lgkmcnt(0)" ::: "memory");
    __builtin_amdgcn_sched_barrier(0);

    // ---- PV: A = P (16q x 64k) from swizzled Pl, B = V from swizzled LDS ----
    short8 pf0 = *reinterpret_cast<const short8*>(plbase + ((l15 * 128 + lhi * 16) ^ swzp));
    short8 pf1 = *reinterpret_cast<const short8*>(plbase + ((l15 * 128 + 64 + lhi * 16) ^ swzp));
    __builtin_amdgcn_s_setprio(1);
#pragma unroll
    for (int c = 0; c < 4; ++c) {
      int d = c * 16 + l15;
      const char* vbase = (const char*)&Vs[cur][0][0] + d * 128;
      short8 vf0 = *reinterpret_cast<const short8*>(vbase + ((lhi ^ (d & 7)) * 16));
      short8 vf1 = *reinterpret_cast<const short8*>(vbase + (((4 + lhi) ^ (d & 7)) * 16));
      o[c] = __builtin_amdgcn_mfma_f32_16x16x32_bf16(pf0, vf0, o[c], 0, 0, 0);
      o[c] = __builtin_amdgcn_mfma_f32_16x16x32_bf16(pf1, vf1, o[c], 0, 0, 0);
    }
    __builtin_amdgcn_s_setprio(0);

    __syncthreads();   // drains vmcnt (next-tile stage) + protects buffers
    cur ^= 1;
  }

  // ---- final denominator: reduce across the 4 lhi copies of each q-row ----
  den += __shfl_xor(den, 16);
  den += __shfl_xor(den, 32);

#pragma unroll
  for (int r = 0; r < 4; ++r) {
    int qo = qw + lhi * 4 + r;
    float dr = __shfl(den, lhi * 4 + r, 64);   // den lives at lanes l15 == q-row
    float dinv = 1.0f / dr;
#pragma unroll
    for (int c = 0; c < 4; ++c)
      AO[(size_t)(b * S_LEN + qo) * HIDDEN + h * DHEAD + c * 16 + l15] = f2bf(o[c][r] * dinv);
  }
}

// ---------------- host ----------------
extern "C" void kernel_launch(void* const* d_in, const int* in_sizes, int n_in,
                              void* d_out, int out_size, void* d_ws, size_t ws_size,
                              hipStream_t stream) {
  const float* hs   = (const float*)d_in[0];
  const float* cosb = (const float*)d_in[1];
  const float* sinb = (const float*)d_in[2];
  const float* Wq   = (const float*)d_in[3];
  const float* Wk   = (const float*)d_in[4];
  const float* Wv   = (const float*)d_in[5];
  const float* Wo   = (const float*)d_in[6];

  char* ws = (char*)d_ws;
  // region A [0, 16.78M): Xbf, later Qr
  unsigned short* Xbf  = (unsigned short*)(ws);
  // region B [16.78M, 29.36M): Wqkv, later Kr + Vt
  unsigned short* Wqkv = (unsigned short*)(ws + 16777216);
  // region C [29.36M, 54.53M): QKV, later AO
  unsigned short* QKV  = (unsigned short*)(ws + 16777216 + 12582912);
  // region D [54.53M, 62.92M): Wo bf16
  unsigned short* Wob  = (unsigned short*)(ws + 16777216 + 12582912 + 25165824);

  unsigned short* Qr = Xbf;
  unsigned short* Kr = Wqkv;
  unsigned short* Vt = (unsigned short*)(ws + 16777216 + 4194304);
  unsigned short* AO = QKV;

  // converts (single merged launch)
  k_cvt5<<<2048, 256, 0, stream>>>(hs, Wq, Wk, Wv, Wo,
                                   Xbf, Wqkv, Wqkv + 4194304, Wqkv + 5242880, Wob);

  // QKV projection: (4096 x 2048) @ (3072 x 2048)^T -> bf16 (4096 x 3072)
  k_gemm8<0><<<dim3(192), 512, 0, stream>>>(Xbf, Wqkv, (void*)QKV, 4096, 3072, 2048, 12);

  // RoPE (Q,K) + V transpose
  k_rope<<<(BATCH * S_LEN * 40 * 32) / 256, 256, 0, stream>>>(QKV, cosb, sinb, Qr, Kr);
  k_vt<<<dim3(S_LEN / 64, BATCH * NKVH), 256, 0, stream>>>(QKV, Vt);

  // attention: 2048 blocks (XCD-swizzled inside), 64 q-rows per block
  k_attn<<<BATCH * NHEAD * (S_LEN / 64), 256, 0, stream>>>(Qr, Kr, Vt, AO);

  // output projection: (4096 x 2048) @ (2048 x 2048)^T -> f32 d_out
  k_gemm8<1><<<dim3(128), 512, 0, stream>>>(AO, Wob, d_out, 4096, 2048, 2048, 8);
}

// Round 6
// 267.193 us; speedup vs baseline: 1.0592x; 1.0592x over previous
//
#include <hip/hip_runtime.h>
#include <hip/hip_bf16.h>
#include <stdint.h>
#include <stddef.h>

#define S_LEN 2048
#define HIDDEN 2048
#define NHEAD 32
#define NKVH 8
#define DHEAD 64
#define BATCH 2
#define HALFW 512
// 0.125 (1/sqrt(64)) * log2(e) folded into Q at RoPE time
#define QSCALE 0.18033688011112042f

typedef __attribute__((ext_vector_type(4))) float f32x4;
typedef __attribute__((ext_vector_type(8))) short short8;
typedef __attribute__((ext_vector_type(4))) short short4v;
typedef __attribute__((ext_vector_type(2))) unsigned int u32x2;

__device__ __forceinline__ unsigned short f2bf(float f) {
  unsigned u = __builtin_bit_cast(unsigned, f);
  u += 0x7fffu + ((u >> 16) & 1u);
  return (unsigned short)(u >> 16);
}
__device__ __forceinline__ float bf2f(unsigned short h) {
  unsigned u = ((unsigned)h) << 16;
  return __builtin_bit_cast(float, u);
}
__device__ __forceinline__ unsigned cvt_pk_bf16(float lo, float hi) {
  unsigned r;
  asm("v_cvt_pk_bf16_f32 %0, %1, %2" : "=v"(r) : "v"(lo), "v"(hi));
  return r;
}
__device__ __forceinline__ f32x4 MF(short8 a, short8 b, f32x4 c) {
  return __builtin_amdgcn_mfma_f32_16x16x32_bf16(a, b, c, 0, 0, 0);
}

// ---------------- merged f32 -> bf16 convert for all 5 tensors ----------------
__global__ void k_cvt5(const float* __restrict__ s0, const float* __restrict__ s1,
                       const float* __restrict__ s2, const float* __restrict__ s3,
                       const float* __restrict__ s4,
                       unsigned short* __restrict__ d0, unsigned short* __restrict__ d1,
                       unsigned short* __restrict__ d2, unsigned short* __restrict__ d3,
                       unsigned short* __restrict__ d4) {
  int i = blockIdx.x * blockDim.x + threadIdx.x;
#pragma unroll 1
  for (int it = 0; it < 9; ++it, i += 524288) {
    const float* src;
    unsigned short* dst;
    int base;
    if (i < 2097152)      { src = s0; dst = d0; base = 0; }
    else if (i < 3145728) { src = s1; dst = d1; base = 2097152; }
    else if (i < 3407872) { src = s2; dst = d2; base = 3145728; }
    else if (i < 3670016) { src = s3; dst = d3; base = 3407872; }
    else                  { src = s4; dst = d4; base = 3670016; }
    int j = i - base;
    float4 v = reinterpret_cast<const float4*>(src)[j];
    short4v o;
    o[0] = (short)f2bf(v.x);
    o[1] = (short)f2bf(v.y);
    o[2] = (short)f2bf(v.z);
    o[3] = (short)f2bf(v.w);
    reinterpret_cast<short4v*>(dst)[j] = o;
  }
}

// ---------------- 8-phase 256x256 bf16 GEMM: C = A[M,K] * W[N,K]^T ----------------
// 8 waves (2M x 4N, wave C = 128x64). BK=64, double-buffered K-tiles, each
// tile split into 128-row halves. Per K-tile: 4 phases of {4-8 ds_read |
// 1 half-tile stage (2 gld_lds) | barrier | 16 MFMA (setprio) | barrier}.
// vmcnt(4) only at phases 4 and 8; never 0 until the peeled last iteration.
// Stage ledger (iter i: tiles t0=2i buf0, t1=2i+1 buf1):
//   ph1: A.h0(t1)  ph2: A.h1(t1)  ph3: B.h0(t2)  ph4: B.h1(t2)+vmcnt(4)
//   ph5: A.h0(t2)  ph6: A.h1(t2)  ph7: B.h0(t3)  ph8: B.h1(t3)+vmcnt(4)
// Each slot's previous contents had its last read >=1 full phase earlier
// (post-MFMA barrier proves reads complete) -> race-free.
// LDS unit map u=(row&7)|(c<<3)|((row>>3)<<6): every 8-lane group of a
// ds_read_b128 covers all 32 banks exactly once (R5-measured 0 conflicts).
#define VM4 asm volatile("s_waitcnt vmcnt(4)" ::: "memory")
#define VM0 asm volatile("s_waitcnt vmcnt(0)" ::: "memory")
#define NOPST (void)0

#define LDA(BUF, FH, KK, J) \
  (*(const short8*)(aL + (BUF)*32768 + (FH)*16384 + (KK)*512 + (J)*4096))
#define LDB(BUF, NF, KK) \
  (*(const short8*)(bL + (BUF)*32768 + ((NF) >> 1)*16384 + ((NF)&1)*8192 + (KK)*512))

#define PHASE(BUF, FH, KK, STAGE_STMT, WAIT_STMT)                              \
  {                                                                            \
    short8 av0 = LDA(BUF, FH, KK, 0), av1 = LDA(BUF, FH, KK, 1),               \
           av2 = LDA(BUF, FH, KK, 2), av3 = LDA(BUF, FH, KK, 3);               \
    if ((FH) == 0) {                                                           \
      bq##KK##0 = LDB(BUF, 0, KK); bq##KK##1 = LDB(BUF, 1, KK);                \
      bq##KK##2 = LDB(BUF, 2, KK); bq##KK##3 = LDB(BUF, 3, KK);                \
    }                                                                          \
    STAGE_STMT;                                                                \
    WAIT_STMT;                                                                 \
    __builtin_amdgcn_s_barrier();                                              \
    __builtin_amdgcn_sched_barrier(0);                                         \
    __builtin_amdgcn_s_setprio(1);                                             \
    acc[(FH)*4 + 0][0] = MF(av0, bq##KK##0, acc[(FH)*4 + 0][0]);               \
    acc[(FH)*4 + 0][1] = MF(av0, bq##KK##1, acc[(FH)*4 + 0][1]);               \
    acc[(FH)*4 + 0][2] = MF(av0, bq##KK##2, acc[(FH)*4 + 0][2]);               \
    acc[(FH)*4 + 0][3] = MF(av0, bq##KK##3, acc[(FH)*4 + 0][3]);               \
    acc[(FH)*4 + 1][0] = MF(av1, bq##KK##0, acc[(FH)*4 + 1][0]);               \
    acc[(FH)*4 + 1][1] = MF(av1, bq##KK##1, acc[(FH)*4 + 1][1]);               \
    acc[(FH)*4 + 1][2] = MF(av1, bq##KK##2, acc[(FH)*4 + 1][2]);               \
    acc[(FH)*4 + 1][3] = MF(av1, bq##KK##3, acc[(FH)*4 + 1][3]);               \
    acc[(FH)*4 + 2][0] = MF(av2, bq##KK##0, acc[(FH)*4 + 2][0]);               \
    acc[(FH)*4 + 2][1] = MF(av2, bq##KK##1, acc[(FH)*4 + 2][1]);               \
    acc[(FH)*4 + 2][2] = MF(av2, bq##KK##2, acc[(FH)*4 + 2][2]);               \
    acc[(FH)*4 + 2][3] = MF(av2, bq##KK##3, acc[(FH)*4 + 2][3]);               \
    acc[(FH)*4 + 3][0] = MF(av3, bq##KK##0, acc[(FH)*4 + 3][0]);               \
    acc[(FH)*4 + 3][1] = MF(av3, bq##KK##1, acc[(FH)*4 + 3][1]);               \
    acc[(FH)*4 + 3][2] = MF(av3, bq##KK##2, acc[(FH)*4 + 3][2]);               \
    acc[(FH)*4 + 3][3] = MF(av3, bq##KK##3, acc[(FH)*4 + 3][3]);               \
    __builtin_amdgcn_s_setprio(0);                                             \
    __builtin_amdgcn_sched_barrier(0);                                         \
    __builtin_amdgcn_s_barrier();                                              \
  }

// CSTORE_MODE: 0 = bf16 store, 1 = f32 store, 2 = f32 atomic add (split-K)
template <int CSTORE_MODE>
__global__ __launch_bounds__(512, 2) void k_gemm8p(const unsigned short* __restrict__ A,
                                                   const unsigned short* __restrict__ Bw,
                                                   void* __restrict__ Cout,
                                                   int M, int N, int K,
                                                   int ntx, int kslices) {
  __shared__ unsigned short As[2][2][8192];  // [buf][half][128r x 64k], 64 KB
  __shared__ unsigned short Bs[2][2][8192];  // 64 KB
  const int tid = threadIdx.x;
  const int lane = tid & 63;
  const int w = tid >> 6;
  const int l15 = lane & 15, lhi = lane >> 4;
  const int wm = w >> 2, wn = w & 3;

  // XCD-chunked swizzle over the whole grid (grid divisible by 8)
  const int cpx = (int)gridDim.x >> 3;
  const int bid = blockIdx.x;
  const int swz = (bid & 7) * cpx + (bid >> 3);
  const int ntiles = (int)gridDim.x / kslices;
  const int ks = swz / ntiles;
  const int tile = swz - ks * ntiles;
  const int ty = tile / ntx, tx = tile - ty * ntx;
  const int bm = ty * 256, bn = tx * 256;
  const int Kslice = K / kslices;
  const int NT = Kslice >> 6;          // 64-wide K-tiles (even, >= 4)
  const int NI = NT >> 1;

  const unsigned short* Ab = A + (size_t)bm * K + (size_t)ks * Kslice;
  const unsigned short* Bb = Bw + (size_t)bn * K + (size_t)ks * Kslice;

  // per-thread stage source (identity unit map u = tid / u = 512+tid)
  const int srow = (tid & 7) | ((tid >> 6) << 3);   // 0..63
  const int sc = (tid >> 3) & 7;
  const unsigned short* sA = Ab + (size_t)srow * K + sc * 8;
  const unsigned short* sB = Bb + (size_t)srow * K + sc * 8;
  char* dA = (char*)&As[0][0][0] + tid * 16;
  char* dB = (char*)&Bs[0][0][0] + tid * 16;

  auto stageA = [&](int buf, int half, int t) {
    const unsigned short* s = sA + (size_t)half * 128 * K + t * 64;
    char* d = dA + buf * 32768 + half * 16384;
    __builtin_amdgcn_global_load_lds(
        (const __attribute__((address_space(1))) unsigned int*)(const void*)s,
        (__attribute__((address_space(3))) unsigned int*)(void*)d, 16, 0, 0);
    __builtin_amdgcn_global_load_lds(
        (const __attribute__((address_space(1))) unsigned int*)(const void*)(s + (size_t)64 * K),
        (__attribute__((address_space(3))) unsigned int*)(void*)(d + 8192), 16, 0, 0);
  };
  auto stageB = [&](int buf, int half, int t) {
    const unsigned short* s = sB + (size_t)half * 128 * K + t * 64;
    char* d = dB + buf * 32768 + half * 16384;
    __builtin_amdgcn_global_load_lds(
        (const __attribute__((address_space(1))) unsigned int*)(const void*)s,
        (__attribute__((address_space(3))) unsigned int*)(void*)d, 16, 0, 0);
    __builtin_amdgcn_global_load_lds(
        (const __attribute__((address_space(1))) unsigned int*)(const void*)(s + (size_t)64 * K),
        (__attribute__((address_space(3))) unsigned int*)(void*)(d + 8192), 16, 0, 0);
  };

  // fragment read bases (bank-optimal unit map)
  const int ar = wm * 16 + l15;                       // A row within 32-row band
  const char* aL = (const char*)&As[0][0][0] + (ar & 7) * 16 + (ar >> 3) * 1024 + lhi * 128;
  const int br = wn * 16 + l15;                       // B row within 64-row band
  const char* bL = (const char*)&Bs[0][0][0] + (br & 7) * 16 + (br >> 3) * 1024 + lhi * 128;

  f32x4 acc[8][4] = {};
  short8 bq00, bq01, bq02, bq03, bq10, bq11, bq12, bq13;

  // prologue: K-tile 0 complete, then B(1) left in flight
  stageB(0, 0, 0); stageB(0, 1, 0); stageA(0, 0, 0); stageA(0, 1, 0);
  VM0;
  __builtin_amdgcn_s_barrier();
  stageB(1, 0, 1); stageB(1, 1, 1);

#pragma unroll 1
  for (int i = 0; i < NI - 1; ++i) {
    const int t1 = 2 * i + 1, t2 = 2 * i + 2, t3 = 2 * i + 3;
    PHASE(0, 0, 0, stageA(1, 0, t1), NOPST)
    PHASE(0, 0, 1, stageA(1, 1, t1), NOPST)
    PHASE(0, 1, 0, stageB(0, 0, t2), NOPST)
    PHASE(0, 1, 1, stageB(0, 1, t2), VM4)
    PHASE(1, 0, 0, stageA(0, 0, t2), NOPST)
    PHASE(1, 0, 1, stageA(0, 1, t2), NOPST)
    PHASE(1, 1, 0, stageB(1, 0, t3), NOPST)
    PHASE(1, 1, 1, stageB(1, 1, t3), VM4)
  }
  {  // peeled last iteration: t0 = NT-2 (buf0), t1 = NT-1 (buf1)
    const int t1 = NT - 1;
    PHASE(0, 0, 0, stageA(1, 0, t1), NOPST)
    PHASE(0, 0, 1, stageA(1, 1, t1), NOPST)
    PHASE(0, 1, 0, NOPST, NOPST)
    PHASE(0, 1, 1, NOPST, VM0)
    PHASE(1, 0, 0, NOPST, NOPST)
    PHASE(1, 0, 1, NOPST, NOPST)
    PHASE(1, 1, 0, NOPST, NOPST)
    PHASE(1, 1, 1, NOPST, NOPST)
  }

#pragma unroll
  for (int f = 0; f < 8; ++f) {
#pragma unroll
    for (int rr = 0; rr < 4; ++rr) {
      int row = bm + f * 32 + wm * 16 + lhi * 4 + rr;
#pragma unroll
      for (int nf = 0; nf < 4; ++nf) {
        int col = bn + nf * 64 + wn * 16 + l15;
        float v = acc[f][nf][rr];
        if (CSTORE_MODE == 0)
          ((unsigned short*)Cout)[(size_t)row * N + col] = f2bf(v);
        else if (CSTORE_MODE == 1)
          ((float*)Cout)[(size_t)row * N + col] = v;
        else
          __hip_atomic_fetch_add(&((float*)Cout)[(size_t)row * N + col], v,
                                 __ATOMIC_RELAXED, __HIP_MEMORY_SCOPE_AGENT);
      }
    }
  }
}

// ---------------- RoPE + transpose to (b,h,s,d) for Q and K ----------------
__global__ void k_rope(const unsigned short* __restrict__ qkv,
                       const float* __restrict__ cosb, const float* __restrict__ sinb,
                       unsigned short* __restrict__ Qr, unsigned short* __restrict__ Kr) {
  int idx = blockIdx.x * blockDim.x + threadIdx.x;
  if (idx >= BATCH * S_LEN * 40 * 32) return;
  int d = idx & 31;
  int hh = (idx >> 5) % 40;
  int bs = idx / (40 * 32);
  int s = bs % S_LEN, b = bs / S_LEN;
  int row = b * S_LEN + s;
  float c = cosb[row * DHEAD + d];
  float sn = sinb[row * DHEAD + d];
  int col = (hh < 32) ? (hh * DHEAD + d) : (2048 + (hh - 32) * DHEAD + d);
  const unsigned short* p = qkv + (size_t)row * 3072;
  float x1 = bf2f(p[col]);
  float x2 = bf2f(p[col + 32]);
  float o1 = x1 * c - x2 * sn;
  float o2 = x2 * c + x1 * sn;
  if (hh < 32) {
    size_t o = ((size_t)(b * NHEAD + hh) * S_LEN + s) * DHEAD + d;
    Qr[o] = f2bf(o1 * QSCALE);
    Qr[o + 32] = f2bf(o2 * QSCALE);
  } else {
    size_t o = ((size_t)(b * NKVH + (hh - 32)) * S_LEN + s) * DHEAD + d;
    Kr[o] = f2bf(o1);
    Kr[o + 32] = f2bf(o2);
  }
}

// ---------------- V transpose: (b,s,hk,d) slice of QKV -> Vt (b,hk,d,s) ----------------
__global__ void k_vt(const unsigned short* __restrict__ qkv, unsigned short* __restrict__ Vt) {
  __shared__ unsigned short t[64][68];
  int s0 = blockIdx.x * 64;
  int b = blockIdx.y >> 3, hk = blockIdx.y & 7;
  int tid = threadIdx.x;
#pragma unroll
  for (int it = 0; it < 4; ++it) {
    int u = it * 256 + tid;
    int srow = u >> 4, c4 = u & 15;
    short4v v = *reinterpret_cast<const short4v*>(
        &qkv[(size_t)(b * S_LEN + s0 + srow) * 3072 + 2560 + hk * 64 + c4 * 4]);
    *reinterpret_cast<short4v*>(&t[srow][c4 * 4]) = v;
  }
  __syncthreads();
#pragma unroll
  for (int it = 0; it < 4; ++it) {
    int u = it * 256 + tid;
    int d = u >> 4, s4 = u & 15;
    short4v v;
#pragma unroll
    for (int j = 0; j < 4; ++j) v[j] = t[s4 * 4 + j][d];
    *reinterpret_cast<short4v*>(
        &Vt[((size_t)(b * NKVH + hk) * DHEAD + d) * S_LEN + s0 + s4 * 4]) = v;
  }
}

// ---------------- sliding-window attention (swapped-QK, packed P) ----------------
__global__ __launch_bounds__(256, 4) void k_attn(const unsigned short* __restrict__ Qr,
                                                 const unsigned short* __restrict__ Kr,
                                                 const unsigned short* __restrict__ Vt,
                                                 unsigned short* __restrict__ AO) {
  __shared__ unsigned short Ks[2][64][64];
  __shared__ unsigned short Vs[2][64][64];
  __shared__ unsigned short Pl[4][16][64];

  const int tid = threadIdx.x, w = tid >> 6, lane = tid & 63;
  const int l15 = lane & 15, lhi = lane >> 4;

  int p = blockIdx.x;
  int L = (p & 7) * 256 + (p >> 3);
  int g = L >> 7;
  int b = g >> 3, hk = g & 7;
  int r_ = L & 127;
  int h = hk * 4 + (r_ >> 5);
  int q0b = (r_ & 31) * 64;
  const int qw = q0b + w * 16;

  const unsigned short* Qh = Qr + (size_t)(b * NHEAD + h) * S_LEN * DHEAD;
  const unsigned short* Kh = Kr + (size_t)(b * NKVH + hk) * S_LEN * DHEAD;
  const unsigned short* Vh = Vt + (size_t)(b * NKVH + hk) * DHEAD * S_LEN;

  short8 qf[2];
#pragma unroll
  for (int c = 0; c < 2; ++c)
    qf[c] = *reinterpret_cast<const short8*>(&Qh[(size_t)(qw + l15) * DHEAD + c * 32 + lhi * 8]);

  f32x4 o[4] = {};
  float den = 0.f;
  const int q = qw + l15;
  const int kvisLo = q - HALFW, kvisHi = q + HALFW;

  char* plbase = (char*)&Pl[w][0][0];
  const int swzp = (l15 & 7) << 4;

  int klo = q0b - HALFW; if (klo < 0) klo = 0;
  klo &= ~63;
  int khi = q0b + 63 + HALFW; if (khi > S_LEN - 1) khi = S_LEN - 1;
  const int nt = ((khi + 1 - klo) + 63) >> 6;

  auto stage = [&](int bufidx, int kbb) {
#pragma unroll
    for (int i = 0; i < 2; ++i) {
      int u = i * 256 + tid;
      int row = u >> 3, c16 = u & 7;
      int sc = c16 ^ (row & 7);
      __builtin_amdgcn_global_load_lds(
          (const __attribute__((address_space(1))) unsigned int*)(const void*)
              (Kh + (size_t)(kbb + row) * DHEAD + sc * 8),
          (__attribute__((address_space(3))) unsigned int*)(void*)
              ((char*)&Ks[bufidx][0][0] + u * 16),
          16, 0, 0);
      __builtin_amdgcn_global_load_lds(
          (const __attribute__((address_space(1))) unsigned int*)(const void*)
              (Vh + (size_t)row * S_LEN + kbb + sc * 8),
          (__attribute__((address_space(3))) unsigned int*)(void*)
              ((char*)&Vs[bufidx][0][0] + u * 16),
          16, 0, 0);
    }
  };

  int cur = 0;
  stage(0, klo);
  __syncthreads();

  for (int t = 0; t < nt; ++t) {
    const int kb = klo + t * 64;
    if (t + 1 < nt) stage(cur ^ 1, kb + 64);

    f32x4 sacc[4] = {};
    __builtin_amdgcn_s_setprio(1);
#pragma unroll
    for (int hh = 0; hh < 4; ++hh) {
      int kr = hh * 16 + l15;
      const char* kbase = (const char*)&Ks[cur][0][0] + kr * 128;
      short8 kf0 = *reinterpret_cast<const short8*>(kbase + ((lhi ^ (kr & 7)) * 16));
      short8 kf1 = *reinterpret_cast<const short8*>(kbase + (((4 + lhi) ^ (kr & 7)) * 16));
      sacc[hh] = __builtin_amdgcn_mfma_f32_16x16x32_bf16(kf0, qf[0], sacc[hh], 0, 0, 0);
      sacc[hh] = __builtin_amdgcn_mfma_f32_16x16x32_bf16(kf1, qf[1], sacc[hh], 0, 0, 0);
    }
    __builtin_amdgcn_s_setprio(0);

    const bool inter = (kb >= qw + 15 - HALFW) && (kb + 63 <= qw + HALFW);
    if (inter) {
#pragma unroll
      for (int hh = 0; hh < 4; ++hh) {
        float p0 = __builtin_amdgcn_exp2f(sacc[hh][0]);
        float p1 = __builtin_amdgcn_exp2f(sacc[hh][1]);
        float p2 = __builtin_amdgcn_exp2f(sacc[hh][2]);
        float p3 = __builtin_amdgcn_exp2f(sacc[hh][3]);
        den += (p0 + p1) + (p2 + p3);
        u32x2 pw;
        pw[0] = cvt_pk_bf16(p0, p1);
        pw[1] = cvt_pk_bf16(p2, p3);
        *(u32x2*)(plbase + ((l15 * 128 + hh * 32 + lhi * 8) ^ swzp)) = pw;
      }
    } else {
#pragma unroll
      for (int hh = 0; hh < 4; ++hh) {
        float pp[4];
#pragma unroll
        for (int r = 0; r < 4; ++r) {
          int key = kb + hh * 16 + lhi * 4 + r;
          bool vis = (key >= kvisLo) && (key <= kvisHi);
          pp[r] = vis ? __builtin_amdgcn_exp2f(sacc[hh][r]) : 0.0f;
        }
        den += (pp[0] + pp[1]) + (pp[2] + pp[3]);
        u32x2 pw;
        pw[0] = cvt_pk_bf16(pp[0], pp[1]);
        pw[1] = cvt_pk_bf16(pp[2], pp[3]);
        *(u32x2*)(plbase + ((l15 * 128 + hh * 32 + lhi * 8) ^ swzp)) = pw;
      }
    }
    asm volatile("s_waitcnt lgkmcnt(0)" ::: "memory");
    __builtin_amdgcn_sched_barrier(0);

    short8 pf0 = *reinterpret_cast<const short8*>(plbase + ((l15 * 128 + lhi * 16) ^ swzp));
    short8 pf1 = *reinterpret_cast<const short8*>(plbase + ((l15 * 128 + 64 + lhi * 16) ^ swzp));
    __builtin_amdgcn_s_setprio(1);
#pragma unroll
    for (int c = 0; c < 4; ++c) {
      int d = c * 16 + l15;
      const char* vbase = (const char*)&Vs[cur][0][0] + d * 128;
      short8 vf0 = *reinterpret_cast<const short8*>(vbase + ((lhi ^ (d & 7)) * 16));
      short8 vf1 = *reinterpret_cast<const short8*>(vbase + (((4 + lhi) ^ (d & 7)) * 16));
      o[c] = __builtin_amdgcn_mfma_f32_16x16x32_bf16(pf0, vf0, o[c], 0, 0, 0);
      o[c] = __builtin_amdgcn_mfma_f32_16x16x32_bf16(pf1, vf1, o[c], 0, 0, 0);
    }
    __builtin_amdgcn_s_setprio(0);

    __syncthreads();
    cur ^= 1;
  }

  den += __shfl_xor(den, 16);
  den += __shfl_xor(den, 32);

#pragma unroll
  for (int r = 0; r < 4; ++r) {
    int qo = qw + lhi * 4 + r;
    float dr = __shfl(den, lhi * 4 + r, 64);
    float dinv = 1.0f / dr;
#pragma unroll
    for (int c = 0; c < 4; ++c)
      AO[(size_t)(b * S_LEN + qo) * HIDDEN + h * DHEAD + c * 16 + l15] = f2bf(o[c][r] * dinv);
  }
}

// ---------------- host ----------------
extern "C" void kernel_launch(void* const* d_in, const int* in_sizes, int n_in,
                              void* d_out, int out_size, void* d_ws, size_t ws_size,
                              hipStream_t stream) {
  const float* hs   = (const float*)d_in[0];
  const float* cosb = (const float*)d_in[1];
  const float* sinb = (const float*)d_in[2];
  const float* Wq   = (const float*)d_in[3];
  const float* Wk   = (const float*)d_in[4];
  const float* Wv   = (const float*)d_in[5];
  const float* Wo   = (const float*)d_in[6];

  char* ws = (char*)d_ws;
  unsigned short* Xbf  = (unsigned short*)(ws);
  unsigned short* Wqkv = (unsigned short*)(ws + 16777216);
  unsigned short* QKV  = (unsigned short*)(ws + 16777216 + 12582912);
  unsigned short* Wob  = (unsigned short*)(ws + 16777216 + 12582912 + 25165824);

  unsigned short* Qr = Xbf;
  unsigned short* Kr = Wqkv;
  unsigned short* Vt = (unsigned short*)(ws + 16777216 + 4194304);
  unsigned short* AO = QKV;

  // converts (single merged launch)
  k_cvt5<<<2048, 256, 0, stream>>>(hs, Wq, Wk, Wv, Wo,
                                   Xbf, Wqkv, Wqkv + 4194304, Wqkv + 5242880, Wob);

  // QKV projection: (4096 x 2048) @ (3072 x 2048)^T -> bf16, 16x12 = 192 tiles
  k_gemm8p<0><<<dim3(192), 512, 0, stream>>>(Xbf, Wqkv, (void*)QKV, 4096, 3072, 2048, 12, 1);

  // RoPE (Q,K) + V transpose
  k_rope<<<(BATCH * S_LEN * 40 * 32) / 256, 256, 0, stream>>>(QKV, cosb, sinb, Qr, Kr);
  k_vt<<<dim3(S_LEN / 64, BATCH * NKVH), 256, 0, stream>>>(QKV, Vt);

  // attention: 2048 blocks (XCD-swizzled inside), 64 q-rows per block
  k_attn<<<BATCH * NHEAD * (S_LEN / 64), 256, 0, stream>>>(Qr, Kr, Vt, AO);

  // output projection: (4096 x 2048) @ (2048 x 2048)^T -> f32 d_out,
  // split-K=2 for full CU coverage (16x8 tiles x 2 = 256 blocks), atomic f32.
  hipMemsetAsync(d_out, 0, (size_t)4096 * 2048 * 4, stream);
  k_gemm8p<2><<<dim3(256), 512, 0, stream>>>(AO, Wob, d_out, 4096, 2048, 2048, 8, 2);
}

// Round 7
// 215.314 us; speedup vs baseline: 1.3144x; 1.2409x over previous
//
#include <hip/hip_runtime.h>
#include <hip/hip_bf16.h>
#include <stdint.h>
#include <stddef.h>

#define S_LEN 2048
#define HIDDEN 2048
#define NHEAD 32
#define NKVH 8
#define DHEAD 64
#define BATCH 2
#define HALFW 512
// 0.125 (1/sqrt(64)) * log2(e) folded into Q at RoPE time
#define QSCALE 0.18033688011112042f

typedef __attribute__((ext_vector_type(4))) float f32x4;
typedef __attribute__((ext_vector_type(8))) short short8;
typedef __attribute__((ext_vector_type(4))) short short4v;
typedef __attribute__((ext_vector_type(2))) unsigned int u32x2;

__device__ __forceinline__ unsigned short f2bf(float f) {
  unsigned u = __builtin_bit_cast(unsigned, f);
  u += 0x7fffu + ((u >> 16) & 1u);
  return (unsigned short)(u >> 16);
}
__device__ __forceinline__ float bf2f(unsigned short h) {
  unsigned u = ((unsigned)h) << 16;
  return __builtin_bit_cast(float, u);
}
__device__ __forceinline__ unsigned cvt_pk_bf16(float lo, float hi) {
  unsigned r;
  asm("v_cvt_pk_bf16_f32 %0, %1, %2" : "=v"(r) : "v"(lo), "v"(hi));
  return r;
}

// ---------------- merged f32 -> bf16 convert for all 5 tensors ----------------
__global__ void k_cvt5(const float* __restrict__ s0, const float* __restrict__ s1,
                       const float* __restrict__ s2, const float* __restrict__ s3,
                       const float* __restrict__ s4,
                       unsigned short* __restrict__ d0, unsigned short* __restrict__ d1,
                       unsigned short* __restrict__ d2, unsigned short* __restrict__ d3,
                       unsigned short* __restrict__ d4) {
  int i = blockIdx.x * blockDim.x + threadIdx.x;
#pragma unroll 1
  for (int it = 0; it < 9; ++it, i += 524288) {
    const float* src;
    unsigned short* dst;
    int base;
    if (i < 2097152)      { src = s0; dst = d0; base = 0; }
    else if (i < 3145728) { src = s1; dst = d1; base = 2097152; }
    else if (i < 3407872) { src = s2; dst = d2; base = 3145728; }
    else if (i < 3670016) { src = s3; dst = d3; base = 3407872; }
    else                  { src = s4; dst = d4; base = 3670016; }
    int j = i - base;
    float4 v = reinterpret_cast<const float4*>(src)[j];
    short4v o;
    o[0] = (short)f2bf(v.x);
    o[1] = (short)f2bf(v.y);
    o[2] = (short)f2bf(v.z);
    o[3] = (short)f2bf(v.w);
    reinterpret_cast<short4v*>(dst)[j] = o;
  }
}

// ---------------- bf16 GEMM: C[M,N] = A[M,K] * W[N,K]^T ----------------
// m97 structure: 128x128 tile, BK=32, 4 waves (each 64x64), global_load_lds w=16.
// MODE 1: f32 store to Cout.
// MODE 2: fused QKV epilogue -- each wave's 64-col chunk is one head; RoPE pair
//   (d, d+32) = acc[m][n] / acc[m][n+2] in the same lane. Q -> Qr (*QSCALE),
//   K -> Kr, V -> Vrow (b,hk,s,d) coalesced.
template <int MODE>
__global__ __launch_bounds__(256) void k_gemm_bt(const unsigned short* __restrict__ A,
                                                 const unsigned short* __restrict__ Bw,
                                                 void* __restrict__ Cout,
                                                 const float* __restrict__ cosb,
                                                 const float* __restrict__ sinb,
                                                 unsigned short* __restrict__ Qr,
                                                 unsigned short* __restrict__ Kr,
                                                 unsigned short* __restrict__ Vrow,
                                                 int M, int N, int K) {
  __shared__ unsigned short As[128][32];
  __shared__ unsigned short Bs[128][32];
  const int tid = threadIdx.x;
  const int wid = tid >> 6;
  const int lane = tid & 63;
  const int l15 = lane & 15;
  const int lhi = lane >> 4;
  const int bm = blockIdx.y * 128;
  const int bn = blockIdx.x * 128;
  const int wm = (wid >> 1) * 64;
  const int wn = (wid & 1) * 64;
  f32x4 acc[4][4] = {};

  for (int k0 = 0; k0 < K; k0 += 32) {
#pragma unroll
    for (int i = 0; i < 2; ++i) {
      int u = i * 256 + tid;          // 512 16B units per 128x32 tile
      int row = u >> 2, c8 = u & 3;
      const unsigned short* ga = A + (size_t)(bm + row) * K + k0 + c8 * 8;
      const unsigned short* gb = Bw + (size_t)(bn + row) * K + k0 + c8 * 8;
      __builtin_amdgcn_global_load_lds(
          (const __attribute__((address_space(1))) unsigned int*)(const void*)ga,
          (__attribute__((address_space(3))) unsigned int*)(void*)((char*)&As[0][0] + i * 4096 + wid * 1024),
          16, 0, 0);
      __builtin_amdgcn_global_load_lds(
          (const __attribute__((address_space(1))) unsigned int*)(const void*)gb,
          (__attribute__((address_space(3))) unsigned int*)(void*)((char*)&Bs[0][0] + i * 4096 + wid * 1024),
          16, 0, 0);
    }
    __syncthreads();   // drains vmcnt (global_load_lds) + makes tile visible

    short8 af[4], bfr[4];
#pragma unroll
    for (int m = 0; m < 4; ++m)
      af[m] = *reinterpret_cast<const short8*>(&As[wm + m * 16 + l15][lhi * 8]);
#pragma unroll
    for (int n = 0; n < 4; ++n)
      bfr[n] = *reinterpret_cast<const short8*>(&Bs[wn + n * 16 + l15][lhi * 8]);
#pragma unroll
    for (int m = 0; m < 4; ++m)
#pragma unroll
      for (int n = 0; n < 4; ++n)
        acc[m][n] = __builtin_amdgcn_mfma_f32_16x16x32_bf16(af[m], bfr[n], acc[m][n], 0, 0, 0);
    __syncthreads();   // all reads done before next stage overwrites
  }

  if (MODE == 1) {
#pragma unroll
    for (int m = 0; m < 4; ++m) {
#pragma unroll
      for (int r = 0; r < 4; ++r) {
        int row = bm + wm + m * 16 + lhi * 4 + r;
#pragma unroll
        for (int n = 0; n < 4; ++n) {
          int col = bn + wn + n * 16 + l15;
          ((float*)Cout)[(size_t)row * N + col] = acc[m][n][r];
        }
      }
    }
  } else {
    // MODE 2: fused RoPE + head-split epilogue
    const int hc = (bn + wn) >> 6;     // head chunk 0..47 (wave-uniform)
#pragma unroll
    for (int m = 0; m < 4; ++m) {
#pragma unroll
      for (int r = 0; r < 4; ++r) {
        int row = bm + wm + m * 16 + lhi * 4 + r;   // = b*2048 + s
        int b = row >> 11, s = row & 2047;
        if (hc < 40) {
#pragma unroll
          for (int n = 0; n < 2; ++n) {
            int d = n * 16 + l15;
            float c = cosb[(size_t)row * DHEAD + d];
            float sn = sinb[(size_t)row * DHEAD + d];
            float x1 = acc[m][n][r];
            float x2 = acc[m][n + 2][r];
            float o1 = x1 * c - x2 * sn;
            float o2 = x2 * c + x1 * sn;
            if (hc < 32) {
              size_t o = ((size_t)(b * NHEAD + hc) * S_LEN + s) * DHEAD + d;
              Qr[o] = f2bf(o1 * QSCALE);
              Qr[o + 32] = f2bf(o2 * QSCALE);
            } else {
              size_t o = ((size_t)(b * NKVH + (hc - 32)) * S_LEN + s) * DHEAD + d;
              Kr[o] = f2bf(o1);
              Kr[o + 32] = f2bf(o2);
            }
          }
        } else {
#pragma unroll
          for (int n = 0; n < 4; ++n) {
            int d = n * 16 + l15;
            size_t o = ((size_t)(b * NKVH + (hc - 40)) * S_LEN + s) * DHEAD + d;
            Vrow[o] = f2bf(acc[m][n][r]);
          }
        }
      }
    }
  }
}

// ---------------- V transpose: Vrow (b,hk,s,d) -> Vt (b,hk,d,s) ----------------
__global__ void k_vt(const unsigned short* __restrict__ Vrow, unsigned short* __restrict__ Vt) {
  __shared__ unsigned short t[64][68];   // 64 s-rows x 64 d-cols, padded
  int s0 = blockIdx.x * 64;
  int g = blockIdx.y;                    // b*8 + hk
  int tid = threadIdx.x;
#pragma unroll
  for (int it = 0; it < 4; ++it) {
    int u = it * 256 + tid;
    int srow = u >> 4, c4 = u & 15;
    short4v v = *reinterpret_cast<const short4v*>(
        &Vrow[((size_t)g * S_LEN + s0 + srow) * DHEAD + c4 * 4]);
    *reinterpret_cast<short4v*>(&t[srow][c4 * 4]) = v;
  }
  __syncthreads();
#pragma unroll
  for (int it = 0; it < 4; ++it) {
    int u = it * 256 + tid;
    int d = u >> 4, s4 = u & 15;
    short4v v;
#pragma unroll
    for (int j = 0; j < 4; ++j) v[j] = t[s4 * 4 + j][d];
    *reinterpret_cast<short4v*>(
        &Vt[((size_t)g * DHEAD + d) * S_LEN + s0 + s4 * 4]) = v;
  }
}

// ---------------- sliding-window attention (swapped-QK, packed P) ----------------
__global__ __launch_bounds__(256, 4) void k_attn(const unsigned short* __restrict__ Qr,
                                                 const unsigned short* __restrict__ Kr,
                                                 const unsigned short* __restrict__ Vt,
                                                 unsigned short* __restrict__ AO) {
  __shared__ unsigned short Ks[2][64][64];
  __shared__ unsigned short Vs[2][64][64];
  __shared__ unsigned short Pl[4][16][64];

  const int tid = threadIdx.x, w = tid >> 6, lane = tid & 63;
  const int l15 = lane & 15, lhi = lane >> 4;

  int p = blockIdx.x;
  int L = (p & 7) * 256 + (p >> 3);
  int g = L >> 7;
  int b = g >> 3, hk = g & 7;
  int r_ = L & 127;
  int h = hk * 4 + (r_ >> 5);
  int q0b = (r_ & 31) * 64;
  const int qw = q0b + w * 16;

  const unsigned short* Qh = Qr + (size_t)(b * NHEAD + h) * S_LEN * DHEAD;
  const unsigned short* Kh = Kr + (size_t)(b * NKVH + hk) * S_LEN * DHEAD;
  const unsigned short* Vh = Vt + (size_t)(b * NKVH + hk) * DHEAD * S_LEN;

  short8 qf[2];
#pragma unroll
  for (int c = 0; c < 2; ++c)
    qf[c] = *reinterpret_cast<const short8*>(&Qh[(size_t)(qw + l15) * DHEAD + c * 32 + lhi * 8]);

  f32x4 o[4] = {};
  float den = 0.f;
  const int q = qw + l15;
  const int kvisLo = q - HALFW, kvisHi = q + HALFW;

  char* plbase = (char*)&Pl[w][0][0];
  const int swzp = (l15 & 7) << 4;

  int klo = q0b - HALFW; if (klo < 0) klo = 0;
  klo &= ~63;
  int khi = q0b + 63 + HALFW; if (khi > S_LEN - 1) khi = S_LEN - 1;
  const int nt = ((khi + 1 - klo) + 63) >> 6;

  auto stage = [&](int bufidx, int kbb) {
#pragma unroll
    for (int i = 0; i < 2; ++i) {
      int u = i * 256 + tid;
      int row = u >> 3, c16 = u & 7;
      int sc = c16 ^ (row & 7);
      __builtin_amdgcn_global_load_lds(
          (const __attribute__((address_space(1))) unsigned int*)(const void*)
              (Kh + (size_t)(kbb + row) * DHEAD + sc * 8),
          (__attribute__((address_space(3))) unsigned int*)(void*)
              ((char*)&Ks[bufidx][0][0] + u * 16),
          16, 0, 0);
      __builtin_amdgcn_global_load_lds(
          (const __attribute__((address_space(1))) unsigned int*)(const void*)
              (Vh + (size_t)row * S_LEN + kbb + sc * 8),
          (__attribute__((address_space(3))) unsigned int*)(void*)
              ((char*)&Vs[bufidx][0][0] + u * 16),
          16, 0, 0);
    }
  };

  int cur = 0;
  stage(0, klo);
  __syncthreads();

  for (int t = 0; t < nt; ++t) {
    const int kb = klo + t * 64;
    if (t + 1 < nt) stage(cur ^ 1, kb + 64);

    f32x4 sacc[4] = {};
    __builtin_amdgcn_s_setprio(1);
#pragma unroll
    for (int hh = 0; hh < 4; ++hh) {
      int kr = hh * 16 + l15;
      const char* kbase = (const char*)&Ks[cur][0][0] + kr * 128;
      short8 kf0 = *reinterpret_cast<const short8*>(kbase + ((lhi ^ (kr & 7)) * 16));
      short8 kf1 = *reinterpret_cast<const short8*>(kbase + (((4 + lhi) ^ (kr & 7)) * 16));
      sacc[hh] = __builtin_amdgcn_mfma_f32_16x16x32_bf16(kf0, qf[0], sacc[hh], 0, 0, 0);
      sacc[hh] = __builtin_amdgcn_mfma_f32_16x16x32_bf16(kf1, qf[1], sacc[hh], 0, 0, 0);
    }
    __builtin_amdgcn_s_setprio(0);

    const bool inter = (kb >= qw + 15 - HALFW) && (kb + 63 <= qw + HALFW);
    if (inter) {
#pragma unroll
      for (int hh = 0; hh < 4; ++hh) {
        float p0 = __builtin_amdgcn_exp2f(sacc[hh][0]);
        float p1 = __builtin_amdgcn_exp2f(sacc[hh][1]);
        float p2 = __builtin_amdgcn_exp2f(sacc[hh][2]);
        float p3 = __builtin_amdgcn_exp2f(sacc[hh][3]);
        den += (p0 + p1) + (p2 + p3);
        u32x2 pw;
        pw[0] = cvt_pk_bf16(p0, p1);
        pw[1] = cvt_pk_bf16(p2, p3);
        *(u32x2*)(plbase + ((l15 * 128 + hh * 32 + lhi * 8) ^ swzp)) = pw;
      }
    } else {
#pragma unroll
      for (int hh = 0; hh < 4; ++hh) {
        float pp[4];
#pragma unroll
        for (int r = 0; r < 4; ++r) {
          int key = kb + hh * 16 + lhi * 4 + r;
          bool vis = (key >= kvisLo) && (key <= kvisHi);
          pp[r] = vis ? __builtin_amdgcn_exp2f(sacc[hh][r]) : 0.0f;
        }
        den += (pp[0] + pp[1]) + (pp[2] + pp[3]);
        u32x2 pw;
        pw[0] = cvt_pk_bf16(pp[0], pp[1]);
        pw[1] = cvt_pk_bf16(pp[2], pp[3]);
        *(u32x2*)(plbase + ((l15 * 128 + hh * 32 + lhi * 8) ^ swzp)) = pw;
      }
    }
    asm volatile("s_waitcnt lgkmcnt(0)" ::: "memory");
    __builtin_amdgcn_sched_barrier(0);

    short8 pf0 = *reinterpret_cast<const short8*>(plbase + ((l15 * 128 + lhi * 16) ^ swzp));
    short8 pf1 = *reinterpret_cast<const short8*>(plbase + ((l15 * 128 + 64 + lhi * 16) ^ swzp));
    __builtin_amdgcn_s_setprio(1);
#pragma unroll
    for (int c = 0; c < 4; ++c) {
      int d = c * 16 + l15;
      const char* vbase = (const char*)&Vs[cur][0][0] + d * 128;
      short8 vf0 = *reinterpret_cast<const short8*>(vbase + ((lhi ^ (d & 7)) * 16));
      short8 vf1 = *reinterpret_cast<const short8*>(vbase + (((4 + lhi) ^ (d & 7)) * 16));
      o[c] = __builtin_amdgcn_mfma_f32_16x16x32_bf16(pf0, vf0, o[c], 0, 0, 0);
      o[c] = __builtin_amdgcn_mfma_f32_16x16x32_bf16(pf1, vf1, o[c], 0, 0, 0);
    }
    __builtin_amdgcn_s_setprio(0);

    __syncthreads();
    cur ^= 1;
  }

  den += __shfl_xor(den, 16);
  den += __shfl_xor(den, 32);

#pragma unroll
  for (int r = 0; r < 4; ++r) {
    int qo = qw + lhi * 4 + r;
    float dr = __shfl(den, lhi * 4 + r, 64);
    float dinv = 1.0f / dr;
#pragma unroll
    for (int c = 0; c < 4; ++c)
      AO[(size_t)(b * S_LEN + qo) * HIDDEN + h * DHEAD + c * 16 + l15] = f2bf(o[c][r] * dinv);
  }
}

// ---------------- host ----------------
extern "C" void kernel_launch(void* const* d_in, const int* in_sizes, int n_in,
                              void* d_out, int out_size, void* d_ws, size_t ws_size,
                              hipStream_t stream) {
  const float* hs   = (const float*)d_in[0];
  const float* cosb = (const float*)d_in[1];
  const float* sinb = (const float*)d_in[2];
  const float* Wq   = (const float*)d_in[3];
  const float* Wk   = (const float*)d_in[4];
  const float* Wv   = (const float*)d_in[5];
  const float* Wo   = (const float*)d_in[6];

  char* ws = (char*)d_ws;
  // ws layout (within the proven 62.92 MB envelope):
  unsigned short* Xbf  = (unsigned short*)(ws);                       // 16.78 MB
  unsigned short* Wqkv = (unsigned short*)(ws + 16777216);            // 12.58 MB
  unsigned short* Vt   = (unsigned short*)(ws + 29360128);            //  4.19 MB
  unsigned short* AO   = (unsigned short*)(ws + 33554432);            // 16.78 MB
  unsigned short* Wob  = (unsigned short*)(ws + 54525952);            //  8.39 MB

  // Q/K/Vrow scratch lives in d_out (25.2 MB <= 33.5 MB); dead before the
  // output projection overwrites d_out.
  unsigned short* Qr   = (unsigned short*)d_out;                      // 16.78 MB
  unsigned short* Kr   = Qr + (size_t)BATCH * NKVH * S_LEN * DHEAD * 4; // 4.19 MB
  unsigned short* Vrow = Kr + (size_t)BATCH * NKVH * S_LEN * DHEAD;     // 4.19 MB

  // converts (single merged launch)
  k_cvt5<<<2048, 256, 0, stream>>>(hs, Wq, Wk, Wv, Wo,
                                   Xbf, Wqkv, Wqkv + 4194304, Wqkv + 5242880, Wob);

  // QKV projection (4096 x 2048) @ (3072 x 2048)^T with fused RoPE/head-split
  k_gemm_bt<2><<<dim3(3072 / 128, 4096 / 128), 256, 0, stream>>>(
      Xbf, Wqkv, nullptr, cosb, sinb, Qr, Kr, Vrow, 4096, 3072, 2048);

  // V transpose (b,hk,s,d) -> (b,hk,d,s)
  k_vt<<<dim3(S_LEN / 64, BATCH * NKVH), 256, 0, stream>>>(Vrow, Vt);

  // attention: 2048 blocks (XCD-swizzled inside), 64 q-rows per block
  k_attn<<<BATCH * NHEAD * (S_LEN / 64), 256, 0, stream>>>(Qr, Kr, Vt, AO);

  // output projection: (4096 x 2048) @ (2048 x 2048)^T -> f32 d_out
  k_gemm_bt<1><<<dim3(2048 / 128, 4096 / 128), 256, 0, stream>>>(
      AO, Wob, d_out, nullptr, nullptr, nullptr, nullptr, nullptr, 4096, 2048, 2048);
}